// Round 1
// baseline (231.636 us; speedup 1.0000x reference)
//
#include <hip/hip_runtime.h>
#include <hip/hip_bf16.h>
#include <math.h>

// Problem: B=16, C=512, N=H*W=4096, K=32
#define BB 16
#define CC 512
#define NN 4096
#define KK 32

typedef __attribute__((ext_vector_type(8))) short short8;
typedef __attribute__((ext_vector_type(4))) short short4v;
typedef __attribute__((ext_vector_type(4))) float float4v;

static __device__ __forceinline__ unsigned short f2bf(float f) {
  unsigned u = __float_as_uint(f);
  u += 0x7FFF + ((u >> 16) & 1);  // RNE
  return (unsigned short)(u >> 16);
}

static __device__ __forceinline__ short8 cat8(short4v a, short4v b) {
  short8 r;
  r[0] = a[0]; r[1] = a[1]; r[2] = a[2]; r[3] = a[3];
  r[4] = b[0]; r[5] = b[1]; r[6] = b[2]; r[7] = b[3];
  return r;
}

// ws layout (bytes):
//   [0,128)        c2   (32 fp32)
//   [128,32896)    cwP  (32 k x 512 c) bf16, c-PERMUTED within 32-blocks:
//                  cwP[k][cs+8q+j] = cw[k][cs + 2q + (j&1) + 8*(j>>1)]
//   [32896,34944)  asum (B*K fp32)
//   [35072,+32MB)  partials: 512 blocks x (32 k x 512 c) fp32

// ---------------- K0: prep (unchanged) ----------------
__global__ __launch_bounds__(256) void prep_kernel(
    const float* __restrict__ cw, unsigned short* __restrict__ cwP,
    float* __restrict__ c2, float* __restrict__ asum) {
  int gid = blockIdx.x * 256 + threadIdx.x;  // 16384 threads = K*C
  if (gid < BB * KK) asum[gid] = 0.f;
  {
    int k = gid >> 9;
    int cc = gid & 511;
    int cs = cc & ~31;
    int w5 = cc & 31;
    int q = w5 >> 3, j = w5 & 7;
    int src_c = cs + 2 * q + (j & 1) + ((j >> 1) << 3);
    cwP[gid] = f2bf(cw[k * CC + src_c]);
  }
  __shared__ float c2p[KK][8];
  if (blockIdx.x == 0) {
    int k = threadIdx.x >> 3, j = threadIdx.x & 7;
    const float* row = cw + k * CC + j * 64;
    float s = 0.f;
    for (int i = 0; i < 64; ++i) s = fmaf(row[i], row[i], s);
    c2p[k][j] = s;
    __syncthreads();
    if (threadIdx.x < KK) {
      float t = 0.f;
      for (int j2 = 0; j2 < 8; ++j2) t += c2p[threadIdx.x][j2];
      c2[threadIdx.x] = t;
    }
  }
}

// ---------------- K1: fused logits->softmax->aggregate ----------------
// v2: 4 subs of 32 n (was 2x64). LDS 39.8 KB -> 4 blocks/CU = 16 waves/CU
// (was 78.8 KB -> 2 blocks = 8 waves). Phase-1/softmax run on 2 of the 4
// waves (only 2 n-tiles of 16 exist); role rotated by block parity so heavy
// waves spread across SIMDs. XP2=36: gather stays ~conflict-free (q-stride
// 36 dwords = 4 mod 32); rows are 8B-aligned so phase-2 frags use b64 pairs
// (16 rows x 18-dword stride -> 16 distinct bank-pairs, conflict-free).
#define XP2 36
__global__ __launch_bounds__(256, 4) void fused_kernel(
    const float* __restrict__ x, const unsigned short* __restrict__ cwP,
    const float* __restrict__ c2g, const float* __restrict__ scale,
    float* __restrict__ partials, float* __restrict__ asum) {
  const int b = blockIdx.x >> 5;
  const int chunk = blockIdx.x & 31;
  const int t = threadIdx.x;
  const int w = t >> 6;
  const int l = t & 63;
  const int l15 = l & 15;
  const int q = l >> 4;
  // rotate heavy-wave role by block parity (wave->SIMD is w%4)
  const int wrole = (w + ((blockIdx.x & 1) << 1)) & 3;

  __shared__ unsigned short Xl[CC * XP2];  // 36864 B
  __shared__ unsigned short As[KK * XP2];  // 2304 B
  __shared__ float Sx2w[4 * 32];           // 512 B  per-wave x2 partials
  __shared__ float Sx2[32];                // 128 B  -> total 39808 B

  const float* xb0 = x + (size_t)b * CC * NN + chunk * 128;

  const float sc0 = scale[l15], sc1 = scale[16 + l15];
  const float cc0 = c2g[l15], cc1 = c2g[16 + l15];

  float4v acc[8][2];
#pragma unroll
  for (int ct = 0; ct < 8; ++ct)
#pragma unroll
    for (int m = 0; m < 2; ++m) acc[ct][m] = (float4v){0.f, 0.f, 0.f, 0.f};
  float s0acc = 0.f, s1acc = 0.f;

  const int f4 = t & 7;   // staging: n = 4*f4 .. 4*f4+3 (32 n per sub)
  const int cr = t >> 3;  // staging: c = cr + 32*i

  for (int sub = 0; sub < 4; ++sub) {
    const float* xb = xb0 + sub * 32;

    // ---- stage x -> Xl bf16; x2 partial per thread (16 c's)
    float4v x2p = (float4v){0.f, 0.f, 0.f, 0.f};
#pragma unroll 8
    for (int i = 0; i < 16; ++i) {
      const int c = cr + 32 * i;
      float4v v = *(const float4v*)(xb + (size_t)c * NN + 4 * f4);
      x2p.x = fmaf(v.x, v.x, x2p.x);
      x2p.y = fmaf(v.y, v.y, x2p.y);
      x2p.z = fmaf(v.z, v.z, x2p.z);
      x2p.w = fmaf(v.w, v.w, x2p.w);
      unsigned p0 = (unsigned)f2bf(v.x) | ((unsigned)f2bf(v.y) << 16);
      unsigned p1 = (unsigned)f2bf(v.z) | ((unsigned)f2bf(v.w) << 16);
      *(uint2*)&Xl[c * XP2 + 4 * f4] = make_uint2(p0, p1);
    }
    // in-wave reduce over the wave's 8 c-rows (lane bits 3,4,5)
#pragma unroll
    for (int m = 8; m <= 32; m <<= 1) {
      x2p.x += __shfl_xor(x2p.x, m);
      x2p.y += __shfl_xor(x2p.y, m);
      x2p.z += __shfl_xor(x2p.z, m);
      x2p.w += __shfl_xor(x2p.w, m);
    }
    if (l < 8) *(float4v*)&Sx2w[w * 32 + 4 * l] = x2p;
    __syncthreads();  // Xl + Sx2w visible

    // ---- phase 1 (waves wrole 0,1): xc via MFMA with permuted c-gather;
    //      wave wrole 2: finish x2 cross-wave sum
    float4v p0 = (float4v){0.f, 0.f, 0.f, 0.f};
    float4v p1 = (float4v){0.f, 0.f, 0.f, 0.f};
    if (wrole < 2) {
      const int nrow = wrole * 16 + l15;
      for (int cs = 0; cs < 512; cs += 32) {
        const int cb2 = cs + 2 * q;
        short8 af;
#pragma unroll
        for (int j = 0; j < 8; ++j) {
          const int c = cb2 + (j & 1) + ((j >> 1) << 3);
          af[j] = (short)Xl[c * XP2 + nrow];
        }
        short8 b0 = *(const short8*)(cwP + (size_t)l15 * CC + cs + q * 8);
        short8 b1 = *(const short8*)(cwP + (size_t)(16 + l15) * CC + cs + q * 8);
        p0 = __builtin_amdgcn_mfma_f32_16x16x32_bf16(af, b0, p0, 0, 0, 0);
        p1 = __builtin_amdgcn_mfma_f32_16x16x32_bf16(af, b1, p1, 0, 0, 0);
      }
    } else if (wrole == 2 && l < 32) {
      Sx2[l] = Sx2w[l] + Sx2w[32 + l] + Sx2w[64 + l] + Sx2w[96 + l];
    }
    __syncthreads();  // Sx2 ready

    // ---- softmax per n (waves wrole 0,1): k spread over l15 lanes
    if (wrole < 2) {
      float a0[4], a1[4];
#pragma unroll
      for (int r = 0; r < 4; ++r) {
        const float xx = Sx2[wrole * 16 + 4 * q + r];
        float l0 = sc0 * (xx - 2.f * p0[r] + cc0);
        float l1 = sc1 * (xx - 2.f * p1[r] + cc1);
        float m = fmaxf(l0, l1);
        m = fmaxf(m, __shfl_xor(m, 1));
        m = fmaxf(m, __shfl_xor(m, 2));
        m = fmaxf(m, __shfl_xor(m, 4));
        m = fmaxf(m, __shfl_xor(m, 8));
        float e0 = __expf(l0 - m), e1 = __expf(l1 - m);
        float s = e0 + e1;
        s += __shfl_xor(s, 1);
        s += __shfl_xor(s, 2);
        s += __shfl_xor(s, 4);
        s += __shfl_xor(s, 8);
        float inv = 1.0f / s;
        a0[r] = e0 * inv;
        a1[r] = e1 * inv;
      }
      s0acc += a0[0] + a0[1] + a0[2] + a0[3];
      s1acc += a1[0] + a1[1] + a1[2] + a1[3];
      unsigned p00 = (unsigned)f2bf(a0[0]) | ((unsigned)f2bf(a0[1]) << 16);
      unsigned p01 = (unsigned)f2bf(a0[2]) | ((unsigned)f2bf(a0[3]) << 16);
      unsigned p10 = (unsigned)f2bf(a1[0]) | ((unsigned)f2bf(a1[1]) << 16);
      unsigned p11 = (unsigned)f2bf(a1[2]) | ((unsigned)f2bf(a1[3]) << 16);
      const int nc = wrole * 16 + 4 * q;
      *(uint2*)&As[l15 * XP2 + nc] = make_uint2(p00, p01);
      *(uint2*)&As[(16 + l15) * XP2 + nc] = make_uint2(p10, p11);
    }
    __syncthreads();  // As ready

    // ---- phase 2 (all waves): out_tile[k][c] += A . x^T over 32 n
    {
      const int nb = q * 8;
      const short4v* Ap0 = (const short4v*)&As[l15 * XP2 + nb];
      const short4v* Ap1 = (const short4v*)&As[(16 + l15) * XP2 + nb];
      short8 am0 = cat8(Ap0[0], Ap0[1]);
      short8 am1 = cat8(Ap1[0], Ap1[1]);
#pragma unroll
      for (int ct = 0; ct < 8; ++ct) {
        const int c = w * 128 + ct * 16 + l15;
        const short4v* Bp = (const short4v*)&Xl[c * XP2 + nb];
        short8 bx = cat8(Bp[0], Bp[1]);
        acc[ct][0] = __builtin_amdgcn_mfma_f32_16x16x32_bf16(am0, bx, acc[ct][0], 0, 0, 0);
        acc[ct][1] = __builtin_amdgcn_mfma_f32_16x16x32_bf16(am1, bx, acc[ct][1], 0, 0, 0);
      }
    }
    __syncthreads();  // protect Xl/As before next sub's staging
  }

  // ---- epilogue: streaming partial tile [32 k][512 c] for this block
  float* pout = partials + (size_t)blockIdx.x * KK * CC;
#pragma unroll
  for (int ct = 0; ct < 8; ++ct) {
    const int c = w * 128 + ct * 16 + l15;
#pragma unroll
    for (int m = 0; m < 2; ++m)
#pragma unroll
      for (int r = 0; r < 4; ++r) {
        int k = 16 * m + 4 * q + r;
        pout[k * CC + c] = acc[ct][m][r];
      }
  }
  // asum: only the phase-1 waves hold A-sums; reduce over q lanes
  s0acc += __shfl_xor(s0acc, 16);
  s0acc += __shfl_xor(s0acc, 32);
  s1acc += __shfl_xor(s1acc, 16);
  s1acc += __shfl_xor(s1acc, 32);
  if (wrole < 2 && q == 0) {
    atomicAdd(&asum[b * KK + l15], s0acc);
    atomicAdd(&asum[b * KK + 16 + l15], s1acc);
  }
}

// ---------------- K2: out = sum_chunk partials - asum * cw (unchanged) ----
__global__ __launch_bounds__(256) void reduce_kernel(
    const float* __restrict__ partials, const float* __restrict__ asum,
    const float* __restrict__ cw, float* __restrict__ out) {
  int idx = blockIdx.x * 256 + threadIdx.x;  // float4 index, 65536 total
  int b = idx >> 12;
  int k = (idx >> 7) & 31;
  int c4 = idx & 127;

  float4v o = {0.f, 0.f, 0.f, 0.f};
  const float4v* pb = (const float4v*)partials + ((size_t)(b * 32) * KK + k) * 128 + c4;
#pragma unroll 8
  for (int p = 0; p < 32; ++p) {
    float4v v = pb[(size_t)p * KK * 128];
    o.x += v.x;
    o.y += v.y;
    o.z += v.z;
    o.w += v.w;
  }
  float4v wv = ((const float4v*)cw)[k * 128 + c4];
  float a = asum[b * KK + k];
  o.x -= a * wv.x;
  o.y -= a * wv.y;
  o.z -= a * wv.z;
  o.w -= a * wv.w;
  ((float4v*)out)[idx] = o;
}

extern "C" void kernel_launch(void* const* d_in, const int* in_sizes, int n_in,
                              void* d_out, int out_size, void* d_ws, size_t ws_size,
                              hipStream_t stream) {
  const float* x = (const float*)d_in[0];      // (16,512,64,64)
  const float* cw = (const float*)d_in[1];     // (32,512)
  const float* scale = (const float*)d_in[2];  // (32,)
  float* out = (float*)d_out;                  // (16,32,512)
  char* ws = (char*)d_ws;

  float* c2 = (float*)ws;                             // 128 B
  unsigned short* cwP = (unsigned short*)(ws + 128);  // 32 KB
  float* asum = (float*)(ws + 32896);                 // 2 KB
  float* partials = (float*)(ws + 35072);             // 32 MB

  prep_kernel<<<64, 256, 0, stream>>>(cw, cwP, c2, asum);
  fused_kernel<<<512, 256, 0, stream>>>(x, cwP, c2, scale, partials, asum);
  reduce_kernel<<<256, 256, 0, stream>>>(partials, asum, cw, out);
}

// Round 2
// 226.301 us; speedup vs baseline: 1.0236x; 1.0236x over previous
//
#include <hip/hip_runtime.h>
#include <hip/hip_bf16.h>
#include <math.h>

// Problem: B=16, C=512, N=H*W=4096, K=32
#define BB 16
#define CC 512
#define NN 4096
#define KK 32

typedef __attribute__((ext_vector_type(8))) short short8;
typedef __attribute__((ext_vector_type(4))) short short4v;
typedef __attribute__((ext_vector_type(4))) float float4v;

static __device__ __forceinline__ unsigned short f2bf(float f) {
  unsigned u = __float_as_uint(f);
  u += 0x7FFF + ((u >> 16) & 1);  // RNE
  return (unsigned short)(u >> 16);
}

static __device__ __forceinline__ short8 cat8(short4v a, short4v b) {
  short8 r;
  r[0] = a[0]; r[1] = a[1]; r[2] = a[2]; r[3] = a[3];
  r[4] = b[0]; r[5] = b[1]; r[6] = b[2]; r[7] = b[3];
  return r;
}

// ws layout (bytes):
//   [0,128)        c2   (32 fp32)
//   [128,32896)    cwP  (32 k x 512 c) bf16, c-PERMUTED within 32-blocks:
//                  cwP[k][cs+8q+j] = cw[k][cs + 2q + (j&1) + 8*(j>>1)]
//   [32896,34944)  asum (B*K fp32)
//   [35072,...)    partials: NBLK x (32 k x 512 c) fp32
//                  NBLK = 1024 if ws allows (64 MB), else 512 (32 MB)

// ---------------- K0: prep (unchanged) ----------------
__global__ __launch_bounds__(256) void prep_kernel(
    const float* __restrict__ cw, unsigned short* __restrict__ cwP,
    float* __restrict__ c2, float* __restrict__ asum) {
  int gid = blockIdx.x * 256 + threadIdx.x;  // 16384 threads = K*C
  if (gid < BB * KK) asum[gid] = 0.f;
  {
    int k = gid >> 9;
    int cc = gid & 511;
    int cs = cc & ~31;
    int w5 = cc & 31;
    int q = w5 >> 3, j = w5 & 7;
    int src_c = cs + 2 * q + (j & 1) + ((j >> 1) << 3);
    cwP[gid] = f2bf(cw[k * CC + src_c]);
  }
  __shared__ float c2p[KK][8];
  if (blockIdx.x == 0) {
    int k = threadIdx.x >> 3, j = threadIdx.x & 7;
    const float* row = cw + k * CC + j * 64;
    float s = 0.f;
    for (int i = 0; i < 64; ++i) s = fmaf(row[i], row[i], s);
    c2p[k][j] = s;
    __syncthreads();
    if (threadIdx.x < KK) {
      float t = 0.f;
      for (int j2 = 0; j2 < 8; ++j2) t += c2p[threadIdx.x][j2];
      c2[threadIdx.x] = t;
    }
  }
}

// ---------------- K1: fused logits->softmax->aggregate ----------------
// v3: occupancy was GRID-capped (512 blocks = 2 blocks/CU = 8 waves/CU;
// LDS/VGPR allowed 4 blocks). Template on chunks-per-batch:
//   LOG2CH=6: grid 1024, 64 n/chunk (2 subs)  -> 4 blocks/CU, 16 waves/CU
//   LOG2CH=5: grid 512, 128 n/chunk (4 subs)  -> v2 fallback (small ws)
#define XP2 36
template <int LOG2CH>
__global__ __launch_bounds__(256, 4) void fused_kernel(
    const float* __restrict__ x, const unsigned short* __restrict__ cwP,
    const float* __restrict__ c2g, const float* __restrict__ scale,
    float* __restrict__ partials, float* __restrict__ asum) {
  constexpr int CHN = NN >> LOG2CH;  // n per chunk (64 or 128)
  constexpr int SUBS = CHN / 32;     // subs of 32 n (2 or 4)
  const int b = blockIdx.x >> LOG2CH;
  const int chunk = blockIdx.x & ((1 << LOG2CH) - 1);
  const int t = threadIdx.x;
  const int w = t >> 6;
  const int l = t & 63;
  const int l15 = l & 15;
  const int q = l >> 4;
  // rotate heavy-wave role by block index so heavy waves spread across SIMDs
  const int wrole = (w + (blockIdx.x & 3)) & 3;

  __shared__ unsigned short Xl[CC * XP2];  // 36864 B
  __shared__ unsigned short As[KK * XP2];  // 2304 B
  __shared__ float Sx2w[4 * 32];           // 512 B  per-wave x2 partials
  __shared__ float Sx2[32];                // 128 B  -> total 39808 B

  const float* xb0 = x + (size_t)b * CC * NN + chunk * CHN;

  const float sc0 = scale[l15], sc1 = scale[16 + l15];
  const float cc0 = c2g[l15], cc1 = c2g[16 + l15];

  float4v acc[8][2];
#pragma unroll
  for (int ct = 0; ct < 8; ++ct)
#pragma unroll
    for (int m = 0; m < 2; ++m) acc[ct][m] = (float4v){0.f, 0.f, 0.f, 0.f};
  float s0acc = 0.f, s1acc = 0.f;

  const int f4 = t & 7;   // staging: n = 4*f4 .. 4*f4+3 (32 n per sub)
  const int cr = t >> 3;  // staging: c = cr + 32*i

  for (int sub = 0; sub < SUBS; ++sub) {
    const float* xb = xb0 + sub * 32;

    // ---- stage x -> Xl bf16; x2 partial per thread (16 c's)
    float4v x2p = (float4v){0.f, 0.f, 0.f, 0.f};
#pragma unroll 8
    for (int i = 0; i < 16; ++i) {
      const int c = cr + 32 * i;
      float4v v = *(const float4v*)(xb + (size_t)c * NN + 4 * f4);
      x2p.x = fmaf(v.x, v.x, x2p.x);
      x2p.y = fmaf(v.y, v.y, x2p.y);
      x2p.z = fmaf(v.z, v.z, x2p.z);
      x2p.w = fmaf(v.w, v.w, x2p.w);
      unsigned p0 = (unsigned)f2bf(v.x) | ((unsigned)f2bf(v.y) << 16);
      unsigned p1 = (unsigned)f2bf(v.z) | ((unsigned)f2bf(v.w) << 16);
      *(uint2*)&Xl[c * XP2 + 4 * f4] = make_uint2(p0, p1);
    }
    // in-wave reduce over the wave's 8 c-rows (lane bits 3,4,5)
#pragma unroll
    for (int m = 8; m <= 32; m <<= 1) {
      x2p.x += __shfl_xor(x2p.x, m);
      x2p.y += __shfl_xor(x2p.y, m);
      x2p.z += __shfl_xor(x2p.z, m);
      x2p.w += __shfl_xor(x2p.w, m);
    }
    if (l < 8) *(float4v*)&Sx2w[w * 32 + 4 * l] = x2p;
    __syncthreads();  // Xl + Sx2w visible

    // ---- phase 1 (waves wrole 0,1): xc via MFMA with permuted c-gather;
    //      wave wrole 2: finish x2 cross-wave sum
    float4v p0 = (float4v){0.f, 0.f, 0.f, 0.f};
    float4v p1 = (float4v){0.f, 0.f, 0.f, 0.f};
    if (wrole < 2) {
      const int nrow = wrole * 16 + l15;
      for (int cs = 0; cs < 512; cs += 32) {
        const int cb2 = cs + 2 * q;
        short8 af;
#pragma unroll
        for (int j = 0; j < 8; ++j) {
          const int c = cb2 + (j & 1) + ((j >> 1) << 3);
          af[j] = (short)Xl[c * XP2 + nrow];
        }
        short8 b0 = *(const short8*)(cwP + (size_t)l15 * CC + cs + q * 8);
        short8 b1 = *(const short8*)(cwP + (size_t)(16 + l15) * CC + cs + q * 8);
        p0 = __builtin_amdgcn_mfma_f32_16x16x32_bf16(af, b0, p0, 0, 0, 0);
        p1 = __builtin_amdgcn_mfma_f32_16x16x32_bf16(af, b1, p1, 0, 0, 0);
      }
    } else if (wrole == 2 && l < 32) {
      Sx2[l] = Sx2w[l] + Sx2w[32 + l] + Sx2w[64 + l] + Sx2w[96 + l];
    }
    __syncthreads();  // Sx2 ready

    // ---- softmax per n (waves wrole 0,1): k spread over l15 lanes
    if (wrole < 2) {
      float a0[4], a1[4];
#pragma unroll
      for (int r = 0; r < 4; ++r) {
        const float xx = Sx2[wrole * 16 + 4 * q + r];
        float l0 = sc0 * (xx - 2.f * p0[r] + cc0);
        float l1 = sc1 * (xx - 2.f * p1[r] + cc1);
        float m = fmaxf(l0, l1);
        m = fmaxf(m, __shfl_xor(m, 1));
        m = fmaxf(m, __shfl_xor(m, 2));
        m = fmaxf(m, __shfl_xor(m, 4));
        m = fmaxf(m, __shfl_xor(m, 8));
        float e0 = __expf(l0 - m), e1 = __expf(l1 - m);
        float s = e0 + e1;
        s += __shfl_xor(s, 1);
        s += __shfl_xor(s, 2);
        s += __shfl_xor(s, 4);
        s += __shfl_xor(s, 8);
        float inv = 1.0f / s;
        a0[r] = e0 * inv;
        a1[r] = e1 * inv;
      }
      s0acc += a0[0] + a0[1] + a0[2] + a0[3];
      s1acc += a1[0] + a1[1] + a1[2] + a1[3];
      unsigned p00 = (unsigned)f2bf(a0[0]) | ((unsigned)f2bf(a0[1]) << 16);
      unsigned p01 = (unsigned)f2bf(a0[2]) | ((unsigned)f2bf(a0[3]) << 16);
      unsigned p10 = (unsigned)f2bf(a1[0]) | ((unsigned)f2bf(a1[1]) << 16);
      unsigned p11 = (unsigned)f2bf(a1[2]) | ((unsigned)f2bf(a1[3]) << 16);
      const int nc = wrole * 16 + 4 * q;
      *(uint2*)&As[l15 * XP2 + nc] = make_uint2(p00, p01);
      *(uint2*)&As[(16 + l15) * XP2 + nc] = make_uint2(p10, p11);
    }
    __syncthreads();  // As ready

    // ---- phase 2 (all waves): out_tile[k][c] += A . x^T over 32 n
    {
      const int nb = q * 8;
      const short4v* Ap0 = (const short4v*)&As[l15 * XP2 + nb];
      const short4v* Ap1 = (const short4v*)&As[(16 + l15) * XP2 + nb];
      short8 am0 = cat8(Ap0[0], Ap0[1]);
      short8 am1 = cat8(Ap1[0], Ap1[1]);
#pragma unroll
      for (int ct = 0; ct < 8; ++ct) {
        const int c = w * 128 + ct * 16 + l15;
        const short4v* Bp = (const short4v*)&Xl[c * XP2 + nb];
        short8 bx = cat8(Bp[0], Bp[1]);
        acc[ct][0] = __builtin_amdgcn_mfma_f32_16x16x32_bf16(am0, bx, acc[ct][0], 0, 0, 0);
        acc[ct][1] = __builtin_amdgcn_mfma_f32_16x16x32_bf16(am1, bx, acc[ct][1], 0, 0, 0);
      }
    }
    __syncthreads();  // protect Xl/As before next sub's staging
  }

  // ---- epilogue: streaming partial tile [32 k][512 c] for this block
  float* pout = partials + (size_t)blockIdx.x * KK * CC;
#pragma unroll
  for (int ct = 0; ct < 8; ++ct) {
    const int c = w * 128 + ct * 16 + l15;
#pragma unroll
    for (int m = 0; m < 2; ++m)
#pragma unroll
      for (int r = 0; r < 4; ++r) {
        int k = 16 * m + 4 * q + r;
        pout[k * CC + c] = acc[ct][m][r];
      }
  }
  // asum: only the phase-1 waves hold A-sums; reduce over q lanes
  s0acc += __shfl_xor(s0acc, 16);
  s0acc += __shfl_xor(s0acc, 32);
  s1acc += __shfl_xor(s1acc, 16);
  s1acc += __shfl_xor(s1acc, 32);
  if (wrole < 2 && q == 0) {
    atomicAdd(&asum[b * KK + l15], s0acc);
    atomicAdd(&asum[b * KK + 16 + l15], s1acc);
  }
}

// ---------------- K2: out = sum_chunk partials - asum * cw ----------------
template <int LOG2CH>
__global__ __launch_bounds__(256) void reduce_kernel(
    const float* __restrict__ partials, const float* __restrict__ asum,
    const float* __restrict__ cw, float* __restrict__ out) {
  constexpr int P = 1 << LOG2CH;  // partial tiles per batch
  int idx = blockIdx.x * 256 + threadIdx.x;  // float4 index, 65536 total
  int b = idx >> 12;
  int k = (idx >> 7) & 31;
  int c4 = idx & 127;

  float4v o = {0.f, 0.f, 0.f, 0.f};
  const float4v* pb =
      (const float4v*)partials + (((size_t)b << LOG2CH) * KK + k) * 128 + c4;
#pragma unroll 8
  for (int p = 0; p < P; ++p) {
    float4v v = pb[(size_t)p * KK * 128];
    o.x += v.x;
    o.y += v.y;
    o.z += v.z;
    o.w += v.w;
  }
  float4v wv = ((const float4v*)cw)[k * 128 + c4];
  float a = asum[b * KK + k];
  o.x -= a * wv.x;
  o.y -= a * wv.y;
  o.z -= a * wv.z;
  o.w -= a * wv.w;
  ((float4v*)out)[idx] = o;
}

extern "C" void kernel_launch(void* const* d_in, const int* in_sizes, int n_in,
                              void* d_out, int out_size, void* d_ws, size_t ws_size,
                              hipStream_t stream) {
  const float* x = (const float*)d_in[0];      // (16,512,64,64)
  const float* cw = (const float*)d_in[1];     // (32,512)
  const float* scale = (const float*)d_in[2];  // (32,)
  float* out = (float*)d_out;                  // (16,32,512)
  char* ws = (char*)d_ws;

  float* c2 = (float*)ws;                             // 128 B
  unsigned short* cwP = (unsigned short*)(ws + 128);  // 32 KB
  float* asum = (float*)(ws + 32896);                 // 2 KB
  float* partials = (float*)(ws + 35072);             // 32 or 64 MB

  prep_kernel<<<64, 256, 0, stream>>>(cw, cwP, c2, asum);

  const size_t need1024 = 35072 + (size_t)1024 * KK * CC * sizeof(float);
  if (ws_size >= need1024) {
    // grid 1024 = 4 blocks/CU -> 16 waves/CU
    fused_kernel<6><<<1024, 256, 0, stream>>>(x, cwP, c2, scale, partials, asum);
    reduce_kernel<6><<<256, 256, 0, stream>>>(partials, asum, cw, out);
  } else {
    // fallback: v2 configuration (known-good), grid 512
    fused_kernel<5><<<512, 256, 0, stream>>>(x, cwP, c2, scale, partials, asum);
    reduce_kernel<5><<<256, 256, 0, stream>>>(partials, asum, cw, out);
  }
}